// Round 7
// baseline (44.923 us; speedup 1.0000x reference)
//
#include <hip/hip_runtime.h>
#include <hip/hip_fp16.h>

#define B_ 2
#define C_ 32
#define H_ 256
#define W_ 256
#define K_ 4
#define HW_ (H_ * W_)

// ---------------------------------------------------------------------------
// Transpose+convert v (B,C,H,W) fp32 -> vt (B,H*W,C) fp16.
// Each pixel's 32 channels = one contiguous 64B segment (one cache line).
// ---------------------------------------------------------------------------
__global__ __launch_bounds__(256) void transpose_v_kernel(
    const float* __restrict__ v, unsigned int* __restrict__ vt) {
  __shared__ float tile[32][65];  // +1 pad: conflict-free transpose reads
  int t = threadIdx.x;
  int pix0 = blockIdx.x * 64;          // global pixel index in [0, B*HW)
  int b = pix0 >> 16;                  // / HW_
  int pixb = pix0 & (HW_ - 1);
  const float* vb = v + (size_t)b * C_ * HW_;
#pragma unroll
  for (int it = 0; it < 8; ++it) {
    int c = (t >> 6) + it * 4;
    int px = t & 63;
    tile[c][px] = __builtin_nontemporal_load(&vb[(size_t)c * HW_ + pixb + px]);
  }
  __syncthreads();
  unsigned int* vtb = vt + (size_t)pix0 * (C_ / 2);
#pragma unroll
  for (int it = 0; it < 4; ++it) {
    int px = (t >> 4) + it * 16;
    int c2 = t & 15;
    float lo = tile[2 * c2][px];
    float hi = tile[2 * c2 + 1][px];
    __half2 h = __floats2half2_rn(lo, hi);
    unsigned int bits;
    __builtin_memcpy(&bits, &h, 4);
    __builtin_nontemporal_store(bits, &vtb[px * 16 + c2]);  // 64B/px coalesced
  }
}

// ---------------------------------------------------------------------------
// Main kernel. 128 threads per block, 32-px tile of one row; 4096 blocks.
// XCD-batch partition (confirmed R4: FETCH 100->25MB): XCDs 0-3 own batch 0,
// XCDs 4-7 batch 1; each XCD's gather set (vt[b] = 4 MiB) fits its L2.
// Phase 1 stores (exp(-cost), byte-offset) pairs; phase 2 gathers with
// SADDR-form dwordx4 (uniform SGPR base + 32-bit voffset: 1 VALU/load) in
// 18-tap register batches. Single barrier; per-thread softmax denominator.
// launch_bounds(128,3): VGPR cap 168 (R5 lesson: 128 broke the batches),
// 6 blocks/CU resident for cross-block phase overlap.
// ---------------------------------------------------------------------------
__global__ __launch_bounds__(128, 3) void psatt_kernel(
    const float* __restrict__ cost_map, const int* __restrict__ shift_map,
    const unsigned int* __restrict__ vt, float* __restrict__ out) {
  __shared__ float2 lds_eo[36][32];  // (e, byte-off); [m][px] conflict-free
  __shared__ float lds_part[32][4];  // softmax partial sums per (px, k)
  __shared__ float lds_out[32][33];  // stride 33: conflict-free epilogue

  int t = threadIdx.x;
  // XCD-aware decomposition (empirical round-robin: XCD = blockIdx % 8).
  int bid = blockIdx.x;            // 0..4095
  int xcd = bid & 7;
  int slot = bid >> 3;             // 0..511
  int b = xcd >> 2;                // XCDs 0-3 -> batch 0, 4-7 -> batch 1
  int workid = ((xcd & 3) << 9) + slot;  // 0..2047; 64 contiguous rows/XCD
  int y = workid >> 3;             // W/32 = 8 tiles per row
  int x0 = (workid & 7) << 5;

  // ---- phase 1: weights + byte offsets (plain loads: halo L2-reused) ------
  {
    int k = t >> 5;   // 4 k-plane groups of 32 lanes
    int px = t & 31;
    int x = x0 + px;
    const float* cm = cost_map + (size_t)(b * K_ + k) * HW_;
    const int* s0 = shift_map + (size_t)((b * 2 + 0) * K_ + k) * HW_;
    const int* s1 = shift_map + (size_t)((b * 2 + 1) * K_ + k) * HW_;
    float psum = 0.f;
#pragma unroll
    for (int di = 0; di < 3; ++di) {
      int ny = y + di - 1;
      bool yin = (unsigned)ny < (unsigned)H_;
#pragma unroll
      for (int dj = 0; dj < 3; ++dj) {
        int nx = x + dj - 1;
        bool inb = yin && ((unsigned)nx < (unsigned)W_);
        int nidx = ny * W_ + nx;
        float cost;
        int si, sj;
        if (inb) {
          cost = cm[nidx];
          si = s0[nidx] + (1 - di);
          sj = s1[nidx] + (1 - dj);
        } else {
          cost = 10.0f;     // pad value of cost_map
          si = 11 - di;     // pad value 10 + (1 - di)
          sj = 11 - dj;
        }
        float e = __expf(-cost);  // T = 1; no max-sub needed (range safe)
        int ii = min(max(si, 0), H_ - 1);
        int jj = min(max(sj, 0), W_ - 1);
        int m = k * 9 + di * 3 + dj;
        // byte offset of pixel's 64B channel line in vt[b]
        lds_eo[m][px] = make_float2(e, __int_as_float((ii * W_ + jj) << 6));
        psum += e;
      }
    }
    lds_part[px][k] = psum;
  }
  __syncthreads();  // single barrier: lds_eo + lds_part both ready

  // ---- phase 2: gather-sum; SADDR dwordx4; 18-tap register batches --------
  {
    int q = t & 3;      // 16B quad within pixel: channels 8q..8q+7
    int px = t >> 2;    // 0..31
    const char* base = (const char*)vt + (size_t)b * HW_ * 64;  // uniform SGPR
    unsigned int qoff = (unsigned int)(q << 4);
    float acc[8] = {0.f, 0.f, 0.f, 0.f, 0.f, 0.f, 0.f, 0.f};
#pragma unroll
    for (int half = 0; half < 2; ++half) {
      uint4 hv[18];
      float ew[18];
#pragma unroll
      for (int m = 0; m < 18; ++m) {
        float2 eo = lds_eo[half * 18 + m][px];     // one ds_read_b64
        ew[m] = eo.x;
        unsigned int voff = (unsigned int)__float_as_int(eo.y) + qoff;
        hv[m] = *(const uint4*)(base + voff);      // global_load_dwordx4 saddr
      }
#pragma unroll
      for (int m = 0; m < 18; ++m) {
        float e = ew[m];
        __half2 h0, h1, h2, h3;
        __builtin_memcpy(&h0, &hv[m].x, 4);
        __builtin_memcpy(&h1, &hv[m].y, 4);
        __builtin_memcpy(&h2, &hv[m].z, 4);
        __builtin_memcpy(&h3, &hv[m].w, 4);
        float2 f0 = __half22float2(h0);
        float2 f1 = __half22float2(h1);
        float2 f2 = __half22float2(h2);
        float2 f3 = __half22float2(h3);
        acc[0] += e * f0.x; acc[1] += e * f0.y;
        acc[2] += e * f1.x; acc[3] += e * f1.y;
        acc[4] += e * f2.x; acc[5] += e * f2.y;
        acc[6] += e * f3.x; acc[7] += e * f3.y;
      }
    }
    // per-thread softmax denominator (broadcast float4 LDS read)
    float4 ps = *(const float4*)&lds_part[px][0];
    float inv = 1.0f / (ps.x + ps.y + ps.z + ps.w);
#pragma unroll
    for (int j = 0; j < 8; ++j) {
      lds_out[px][8 * q + j] = acc[j] * inv;
    }
  }
  __syncthreads();

  // ---- epilogue: transpose to channel-major, nontemporal coalesced stores -
  {
    int px = t & 31;
#pragma unroll
    for (int it = 0; it < 8; ++it) {
      int c = (t >> 5) + it * 4;
      __builtin_nontemporal_store(
          lds_out[px][c],
          &out[((size_t)(b * C_ + c) * H_ + y) * W_ + x0 + px]);
    }
  }
}

extern "C" void kernel_launch(void* const* d_in, const int* in_sizes, int n_in,
                              void* d_out, int out_size, void* d_ws, size_t ws_size,
                              hipStream_t stream) {
  const float* v = (const float*)d_in[0];
  const float* cost_map = (const float*)d_in[1];
  const int* shift_map = (const int*)d_in[2];
  float* out = (float*)d_out;

  unsigned int* vt = (unsigned int*)d_ws;  // B*HW*16 uints = 8.4 MB
  const int grid = B_ * H_ * (W_ / 32);    // 4096 blocks

  transpose_v_kernel<<<B_ * HW_ / 64, 256, 0, stream>>>(v, vt);
  psatt_kernel<<<grid, 128, 0, stream>>>(cost_map, shift_map, vt, out);
}